// Round 5
// baseline (598.606 us; speedup 1.0000x reference)
//
#include <hip/hip_runtime.h>
#include <hip/hip_bf16.h>
#include <hip/hip_cooperative_groups.h>
#include <stdint.h>

namespace cg = cooperative_groups;

typedef __attribute__((ext_vector_type(8))) short bf16x8;
typedef __attribute__((ext_vector_type(4))) float f32x4;

union FragU { uint4 u; bf16x8 v; };

#define Bn 16
#define Kn 16
#define Sn 512
#define En 512
#define Ln 16
#define Hn 8
#define Dn 64

__device__ __forceinline__ uint32_t pack_bf16(float lo, float hi) {
  uint32_t a = __float_as_uint(lo) + 0x8000u;
  uint32_t b = __float_as_uint(hi) + 0x8000u;
  return __builtin_amdgcn_perm(b, a, 0x07060302u);  // [b.hi16 : a.hi16]
}
__device__ __forceinline__ uint16_t bf16_1(float x) {
  __hip_bfloat16 h = __float2bfloat16(x);
  return *(uint16_t*)&h;
}
__device__ __forceinline__ void gload_lds16(const void* g, void* l) {
  __builtin_amdgcn_global_load_lds(
      (const __attribute__((address_space(1))) uint32_t*)g,
      (__attribute__((address_space(3))) uint32_t*)l, 16, 0, 0);
}

// ==================== Cooperative mega-kernel ====================
// 512 blocks x 256 threads, 2 blocks/CU co-resident (LDS 52KB, VGPR<=256).
// Phase 1: prep (xq, Wsw, Wob)   -> grid.sync
// Phase 2: kvproj, 4 tiles/block -> grid.sync
// Phase 3: attn, 1 block each    -> grid.sync
// Phase 4: oproj 64x64, 1 tile each
union SharedU {
  struct { uint16_t Bs[256*64]; uint16_t As[64*72]; } kv;                       // 41 KB
  struct { uint16_t Ks[128*72]; uint16_t Vts[64*136]; uint16_t Ps[64*136]; } at;// 52 KB
  struct { uint16_t As[64*72]; uint16_t Bs[64*72]; } op;                        // 18 KB
  float red[4][Ln];
};

__global__ __launch_bounds__(256, 2)
void mega_kernel(const float* __restrict__ spike, const int* __restrict__ offsets,
                 const int* __restrict__ lengths, const float* __restrict__ cosT,
                 const float* __restrict__ sinT, const float* __restrict__ latent,
                 const float* __restrict__ Wq, const float* __restrict__ Wk,
                 const float* __restrict__ Wv, const float* __restrict__ Wo,
                 float* __restrict__ xq, uint4* __restrict__ Wsw,
                 uint4* __restrict__ Wob, uint16_t* __restrict__ Kbuf,
                 uint16_t* __restrict__ Vt, uint16_t* __restrict__ attn_out,
                 float* __restrict__ out)
{
  __shared__ __align__(16) SharedU sh;
  cg::grid_group grid = cg::this_grid();
  const int t = threadIdx.x;
  const int b = blockIdx.x;

  // ---------- Phase 1: prep ----------
  {
    if (b < 64) {                       // Wk/Wv -> Wsw (swizzled bf16)
      const int idx = b*256 + t;
      const int kb = idx >> 11;
      const int rem = idx & 2047;
      const int n = rem >> 3, p = rem & 7;
      const int c = p ^ (n & 7);
      const float* src = (n < 128 ? Wk + (size_t)n*En : Wv + (size_t)(n-128)*En) + kb*64 + c*8;
      float4 v0 = *(const float4*)src;
      float4 v1 = *(const float4*)(src+4);
      uint4 o;
      o.x = pack_bf16(v0.x,v0.y); o.y = pack_bf16(v0.z,v0.w);
      o.z = pack_bf16(v1.x,v1.y); o.w = pack_bf16(v1.z,v1.w);
      Wsw[idx] = o;
    } else if (b < 192) {               // Wo -> Wob (row-major bf16)
      const int idx = (b-64)*256 + t;
      const float* src = Wo + (size_t)idx*8;
      float4 v0 = *(const float4*)src;
      float4 v1 = *(const float4*)(src+4);
      uint4 o;
      o.x = pack_bf16(v0.x,v0.y); o.y = pack_bf16(v0.z,v0.w);
      o.z = pack_bf16(v1.x,v1.y); o.w = pack_bf16(v1.z,v1.w);
      Wob[idx] = o;
    }
    // all 512 blocks: xq column j = b
    {
      const int j = b;
      const float w0 = Wq[j*En + t];
      const float w1 = Wq[j*En + t + 256];
      float part[Ln];
#pragma unroll
      for (int l = 0; l < Ln; ++l)
        part[l] = w0 * latent[l*En + t] + w1 * latent[l*En + t + 256];
#pragma unroll
      for (int l = 0; l < Ln; ++l) {
        float v = part[l];
#pragma unroll
        for (int off = 32; off > 0; off >>= 1) v += __shfl_down(v, off, 64);
        part[l] = v;
      }
      const int lane = t & 63, wv = t >> 6;
      if (lane == 0) {
#pragma unroll
        for (int l = 0; l < Ln; ++l) sh.red[wv][l] = part[l];
      }
      __syncthreads();
      if (t < Ln)
        xq[t*En + j] = sh.red[0][t] + sh.red[1][t] + sh.red[2][t] + sh.red[3][t];
    }
  }
  grid.sync();

  // ---------- Phase 2: KV projection (4 tiles per block) ----------
  {
    const int lane = t & 63, wv = t >> 6;
    const int quad = lane >> 4, lr = lane & 15;
    const int arow = t >> 3, aseg = t & 7;

    for (int tl = b; tl < 2048; tl += 512) {
      const int bk = tl >> 3, tile = tl & 7;
      if (tile * 64 >= lengths[bk]) continue;   // ragged skip
      const int m0 = tl * 64;

      f32x4 acc[4][4];
#pragma unroll
      for (int i=0;i<4;i++)
#pragma unroll
        for (int j=0;j<4;j++) acc[i][j] = (f32x4){0.f,0.f,0.f,0.f};

      for (int kb = 0; kb < 8; ++kb) {
        const char* gb = (const char*)(Wsw + kb*2048) + (wv*64 + lane)*16;
        char* lb = (char*)sh.kv.Bs + wv*1024;
#pragma unroll
        for (int i = 0; i < 8; ++i)
          gload_lds16(gb + i*4096, lb + i*4096);
#pragma unroll
        for (int j = 0; j < 2; ++j) {
          const int row = arow + 32*j;
          const float* src = &spike[(size_t)(m0+row)*En + kb*64 + aseg*8];
          float4 v0 = *(const float4*)src;
          float4 v1 = *(const float4*)(src+4);
          uint4 o;
          o.x = pack_bf16(v0.x,v0.y); o.y = pack_bf16(v0.z,v0.w);
          o.z = pack_bf16(v1.x,v1.y); o.w = pack_bf16(v1.z,v1.w);
          *(uint4*)&sh.kv.As[row*72 + aseg*8] = o;
        }
        __syncthreads();
#pragma unroll
        for (int kk = 0; kk < 2; ++kk) {
          const int c = kk*4 + quad;
          FragU aF[4], bF[4];
#pragma unroll
          for (int mi=0;mi<4;mi++) aF[mi].u = *(const uint4*)&sh.kv.As[(mi*16+lr)*72 + c*8];
#pragma unroll
          for (int ni=0;ni<4;ni++) {
            const int n = wv*64 + ni*16 + lr;
            bF[ni].u = *(const uint4*)&sh.kv.Bs[n*64 + (c ^ (n&7))*8];
          }
#pragma unroll
          for (int mi=0;mi<4;mi++)
#pragma unroll
            for (int ni=0;ni<4;ni++)
              acc[mi][ni] = __builtin_amdgcn_mfma_f32_16x16x32_bf16(aF[mi].v, bF[ni].v, acc[mi][ni], 0,0,0);
        }
        __syncthreads();
      }

      const int sbase = m0 & 511;
      if (wv < 2) {
#pragma unroll
        for (int mi=0;mi<4;mi++) {
#pragma unroll
          for (int r=0;r<4;r++) {
            const int s = sbase + mi*16 + quad*4 + r;
            const int off = offsets[m0 + mi*16 + quad*4 + r];
#pragma unroll
            for (int ni=0;ni<4;ni++) {
              const int d = ni*16 + lr;
              const float v = acc[mi][ni][r];
              const float p = acc[mi][ni^2][r];
              const float rot = (ni < 2) ? -p : p;
              const float cc  = cosT[off*Dn + d];
              const float sn  = sinT[off*Dn + d];
              Kbuf[((size_t)(bk*512 + s))*128 + wv*64 + d] = bf16_1(v*cc + rot*sn);
            }
          }
        }
      } else {
        const int nbase = (wv - 2) * 64;
#pragma unroll
        for (int mi=0;mi<4;mi++) {
#pragma unroll
          for (int ni=0;ni<4;ni++) {
            const int np = nbase + ni*16 + lr;
            const int s  = sbase + mi*16 + quad*4;
            uint2 pk;
            pk.x = pack_bf16(acc[mi][ni][0], acc[mi][ni][1]);
            pk.y = pack_bf16(acc[mi][ni][2], acc[mi][ni][3]);
            *(uint2*)&Vt[((size_t)(bk*128 + np))*512 + s] = pk;
          }
        }
      }
    }
  }
  grid.sync();

  // ---------- Phase 3: flash attention (1 per block) ----------
  {
    const int bk = b >> 1, kvh = b & 1;
    const int w = t >> 6, lane = t & 63;
    const int quad = lane >> 4, lr = lane & 15;
    const int h = kvh*4 + w;
    const int len = lengths[bk];
    const int nc = (len + 127) >> 7;   // 1..4 chunks of 128

    FragU aQ[2];
#pragma unroll
    for (int kk=0;kk<2;kk++) {
      const float* qp = &xq[lr*En + h*Dn + kk*32 + quad*8];
      float4 q0 = *(const float4*)qp;
      float4 q1 = *(const float4*)(qp + 4);
      aQ[kk].u.x = pack_bf16(q0.x*0.125f, q0.y*0.125f);
      aQ[kk].u.y = pack_bf16(q0.z*0.125f, q0.w*0.125f);
      aQ[kk].u.z = pack_bf16(q1.x*0.125f, q1.y*0.125f);
      aQ[kk].u.w = pack_bf16(q1.z*0.125f, q1.w*0.125f);
    }

    float m_run[4], l_run[4], alpha[4];
    f32x4 oacc[4];
#pragma unroll
    for (int r=0;r<4;r++){ m_run[r] = -3.0e38f; l_run[r] = 0.f; }
#pragma unroll
    for (int nd=0;nd<4;nd++) oacc[nd] = (f32x4){0.f,0.f,0.f,0.f};

    const int krow = t >> 1, kseg = t & 1;
    const int vrow = t >> 2, vseg = t & 3;
    const uint16_t* gK = &Kbuf[((size_t)(bk*512 + krow))*128 + kvh*64 + kseg*32];
    const uint16_t* gV = &Vt [((size_t)(bk*128 + kvh*64 + vrow))*512 + vseg*32];

    uint4 k0, k1, k2, k3, v0, v1, v2, v3;   // named -> guaranteed VGPRs

#define PREF(c) do {                                           \
    const uint16_t* g_  = gK + (size_t)(c)*16384;              \
    k0 = *(const uint4*)g_;      k1 = *(const uint4*)(g_+8);   \
    k2 = *(const uint4*)(g_+16); k3 = *(const uint4*)(g_+24);  \
    const uint16_t* gv_ = gV + (c)*128;                        \
    v0 = *(const uint4*)gv_;      v1 = *(const uint4*)(gv_+8); \
    v2 = *(const uint4*)(gv_+16); v3 = *(const uint4*)(gv_+24);\
  } while(0)

    PREF(0);

    for (int c = 0; c < nc; ++c) {
      const int s0 = c * 128;
      __syncthreads();
      {
        uint16_t* dst = &sh.at.Ks[krow*72 + kseg*32];
        *(uint4*)dst = k0; *(uint4*)(dst+8) = k1;
        *(uint4*)(dst+16) = k2; *(uint4*)(dst+24) = k3;
        uint16_t* dv = &sh.at.Vts[vrow*136 + vseg*32];
        *(uint4*)dv = v0; *(uint4*)(dv+8) = v1;
        *(uint4*)(dv+16) = v2; *(uint4*)(dv+24) = v3;
      }
      if (c + 1 < nc) PREF(c + 1);               // issue next-chunk loads now
      __builtin_amdgcn_sched_barrier(0);
      asm volatile("s_waitcnt lgkmcnt(0)" ::: "memory");  // vmcnt untouched
      __builtin_amdgcn_s_barrier();
      __builtin_amdgcn_sched_barrier(0);

      f32x4 sc[8];
      __builtin_amdgcn_s_setprio(1);
#pragma unroll
      for (int ni=0;ni<8;ni++) {
        FragU b0, b1;
        b0.u = *(const uint4*)&sh.at.Ks[(ni*16+lr)*72 + quad*8];
        b1.u = *(const uint4*)&sh.at.Ks[(ni*16+lr)*72 + 32 + quad*8];
        f32x4 a = (f32x4){0.f,0.f,0.f,0.f};
        a = __builtin_amdgcn_mfma_f32_16x16x32_bf16(aQ[0].v, b0.v, a, 0,0,0);
        a = __builtin_amdgcn_mfma_f32_16x16x32_bf16(aQ[1].v, b1.v, a, 0,0,0);
        sc[ni] = a;
      }
      __builtin_amdgcn_s_setprio(0);
#pragma unroll
      for (int ni=0;ni<8;ni++)
        if (s0 + ni*16 + lr >= len)
          sc[ni] = (f32x4){-3.0e38f,-3.0e38f,-3.0e38f,-3.0e38f};

#pragma unroll
      for (int r=0;r<4;r++) {
        float mx = sc[0][r];
#pragma unroll
        for (int ni=1;ni<8;ni++) mx = fmaxf(mx, sc[ni][r]);
#pragma unroll
        for (int o=1;o<16;o<<=1) mx = fmaxf(mx, __shfl_xor(mx, o, 16));
        const float mnew = fmaxf(m_run[r], mx);
        alpha[r] = __expf(m_run[r] - mnew);
        m_run[r] = mnew;
        float ssum = 0.f;
#pragma unroll
        for (int ni=0;ni<8;ni++) {
          float p = __expf(sc[ni][r] - mnew);
          sc[ni][r] = p;
          ssum += p;
        }
#pragma unroll
        for (int o=1;o<16;o<<=1) ssum += __shfl_xor(ssum, o, 16);
        l_run[r] = l_run[r]*alpha[r] + ssum;
      }

#pragma unroll
      for (int ni=0;ni<8;ni++)
#pragma unroll
        for (int r=0;r<4;r++)
          sh.at.Ps[(w*16 + quad*4 + r)*136 + ni*16 + lr] = bf16_1(sc[ni][r]);

#pragma unroll
      for (int nd=0;nd<4;nd++)
#pragma unroll
        for (int r=0;r<4;r++) oacc[nd][r] *= alpha[r];

      __builtin_amdgcn_s_setprio(1);
#pragma unroll
      for (int kk=0;kk<4;kk++) {
        FragU aP;
        aP.u = *(const uint4*)&sh.at.Ps[(w*16 + lr)*136 + kk*32 + quad*8];
#pragma unroll
        for (int nd=0;nd<4;nd++) {
          FragU bV;
          bV.u = *(const uint4*)&sh.at.Vts[(nd*16+lr)*136 + kk*32 + quad*8];
          oacc[nd] = __builtin_amdgcn_mfma_f32_16x16x32_bf16(aP.v, bV.v, oacc[nd], 0,0,0);
        }
      }
      __builtin_amdgcn_s_setprio(0);
    }
#undef PREF

#pragma unroll
    for (int r=0;r<4;r++) {
      const float rs = 1.0f / l_run[r];
      const int l = quad*4 + r;
#pragma unroll
      for (int nd=0;nd<4;nd++)
        attn_out[((size_t)(bk*16 + l))*512 + h*64 + nd*16 + lr] = bf16_1(oacc[nd][r] * rs);
    }
  }
  grid.sync();

  // ---------- Phase 4: oproj 64x64 (1 tile per block, full CU coverage) ----------
  {
    const int m0 = (b >> 3) * 64;
    const int n0 = (b & 7) * 64;
    const int lane = t & 63, wv = t >> 6;
    const int quad = lane >> 4, lr = lane & 15;
    const int wm = wv >> 1, wn = wv & 1;

    f32x4 acc[2][2];
#pragma unroll
    for (int i=0;i<2;i++)
#pragma unroll
      for (int j=0;j<2;j++) acc[i][j] = (f32x4){0.f,0.f,0.f,0.f};

    const int srow = t >> 3, sseg = t & 7;
    const uint16_t* Ab  = attn_out;
    const uint16_t* Wb  = (const uint16_t*)Wob;
    for (int kb = 0; kb < 8; ++kb) {
#pragma unroll
      for (int j = 0; j < 2; ++j) {
        const int row = srow + 32*j;
        *(uint4*)&sh.op.As[row*72 + sseg*8] = *(const uint4*)&Ab[(size_t)(m0+row)*512 + kb*64 + sseg*8];
        *(uint4*)&sh.op.Bs[row*72 + sseg*8] = *(const uint4*)&Wb[(size_t)(n0+row)*512 + kb*64 + sseg*8];
      }
      __syncthreads();
#pragma unroll
      for (int kk = 0; kk < 2; ++kk) {
        const int c = kk*4 + quad;
        FragU aF[2], bF[2];
#pragma unroll
        for (int mi=0;mi<2;mi++) aF[mi].u = *(const uint4*)&sh.op.As[(wm*32+mi*16+lr)*72 + c*8];
#pragma unroll
        for (int ni=0;ni<2;ni++) bF[ni].u = *(const uint4*)&sh.op.Bs[(wn*32+ni*16+lr)*72 + c*8];
#pragma unroll
        for (int mi=0;mi<2;mi++)
#pragma unroll
          for (int ni=0;ni<2;ni++)
            acc[mi][ni] = __builtin_amdgcn_mfma_f32_16x16x32_bf16(aF[mi].v, bF[ni].v, acc[mi][ni], 0,0,0);
      }
      __syncthreads();
    }
#pragma unroll
    for (int mi=0;mi<2;mi++)
#pragma unroll
      for (int r=0;r<4;r++)
#pragma unroll
        for (int ni=0;ni<2;ni++)
          out[(size_t)(m0 + wm*32 + mi*16 + quad*4 + r)*512 + n0 + wn*32 + ni*16 + lr] = acc[mi][ni][r];
  }
}

// ==================== Fallback kernels (R4-proven) ====================
__global__ __launch_bounds__(256)
void prep_kernel(const float* __restrict__ latent, const float* __restrict__ Wq,
                 const float* __restrict__ Wk, const float* __restrict__ Wv,
                 const float* __restrict__ Wo,
                 float* __restrict__ xq, uint4* __restrict__ Wsw, uint4* __restrict__ Wob)
{
  __shared__ float red[4][Ln];
  const int t = threadIdx.x;
  const int blk = blockIdx.x;
  if (blk < 512) {
    const int j = blk;
    const float w0 = Wq[j*En + t];
    const float w1 = Wq[j*En + t + 256];
    float part[Ln];
#pragma unroll
    for (int l = 0; l < Ln; ++l)
      part[l] = w0 * latent[l*En + t] + w1 * latent[l*En + t + 256];
#pragma unroll
    for (int l = 0; l < Ln; ++l) {
      float v = part[l];
#pragma unroll
      for (int off = 32; off > 0; off >>= 1) v += __shfl_down(v, off, 64);
      part[l] = v;
    }
    const int lane = t & 63, wv = t >> 6;
    if (lane == 0) {
#pragma unroll
      for (int l = 0; l < Ln; ++l) red[wv][l] = part[l];
    }
    __syncthreads();
    if (t < Ln)
      xq[t*En + j] = red[0][t] + red[1][t] + red[2][t] + red[3][t];
  } else if (blk < 576) {
    const int idx = (blk - 512)*256 + t;
    const int kb = idx >> 11;
    const int rem = idx & 2047;
    const int n = rem >> 3, p = rem & 7;
    const int c = p ^ (n & 7);
    const float* src = (n < 128 ? Wk + (size_t)n*En : Wv + (size_t)(n-128)*En) + kb*64 + c*8;
    float4 v0 = *(const float4*)src;
    float4 v1 = *(const float4*)(src+4);
    uint4 o;
    o.x = pack_bf16(v0.x,v0.y); o.y = pack_bf16(v0.z,v0.w);
    o.z = pack_bf16(v1.x,v1.y); o.w = pack_bf16(v1.z,v1.w);
    Wsw[idx] = o;
  } else {
    const int idx = (blk - 576)*256 + t;
    const float* src = Wo + (size_t)idx*8;
    float4 v0 = *(const float4*)src;
    float4 v1 = *(const float4*)(src+4);
    uint4 o;
    o.x = pack_bf16(v0.x,v0.y); o.y = pack_bf16(v0.z,v0.w);
    o.z = pack_bf16(v1.x,v1.y); o.w = pack_bf16(v1.z,v1.w);
    Wob[idx] = o;
  }
}

__global__ __launch_bounds__(256)
void kvproj_kernel(const float* __restrict__ spike, const int* __restrict__ offsets,
                   const float* __restrict__ cosT, const float* __restrict__ sinT,
                   const uint4* __restrict__ Wsw, const int* __restrict__ lengths,
                   uint16_t* __restrict__ Kbuf, uint16_t* __restrict__ Vt)
{
  __shared__ __align__(16) uint16_t Bs[256*64];
  __shared__ __align__(16) uint16_t As[64*72];
  const int t = threadIdx.x;
  const int bk   = blockIdx.x >> 3;
  const int tile = blockIdx.x & 7;
  if (tile * 64 >= lengths[bk]) return;
  const int m0 = blockIdx.x * 64;
  const int lane = t & 63, wv = t >> 6;
  const int quad = lane >> 4, lr = lane & 15;

  f32x4 acc[4][4];
#pragma unroll
  for (int i=0;i<4;i++)
#pragma unroll
    for (int j=0;j<4;j++) acc[i][j] = (f32x4){0.f,0.f,0.f,0.f};

  const int arow = t >> 3;
  const int aseg = t & 7;

  for (int kb = 0; kb < 8; ++kb) {
    const char* gb = (const char*)(Wsw + kb*2048) + (wv*64 + lane)*16;
    char* lb = (char*)Bs + wv*1024;
#pragma unroll
    for (int i = 0; i < 8; ++i)
      gload_lds16(gb + i*4096, lb + i*4096);
#pragma unroll
    for (int j = 0; j < 2; ++j) {
      const int row = arow + 32*j;
      const float* src = &spike[(size_t)(m0+row)*En + kb*64 + aseg*8];
      float4 v0 = *(const float4*)src;
      float4 v1 = *(const float4*)(src+4);
      uint4 o;
      o.x = pack_bf16(v0.x,v0.y); o.y = pack_bf16(v0.z,v0.w);
      o.z = pack_bf16(v1.x,v1.y); o.w = pack_bf16(v1.z,v1.w);
      *(uint4*)&As[row*72 + aseg*8] = o;
    }
    __syncthreads();
#pragma unroll
    for (int kk = 0; kk < 2; ++kk) {
      const int c = kk*4 + quad;
      FragU aF[4], bF[4];
#pragma unroll
      for (int mi=0;mi<4;mi++) aF[mi].u = *(const uint4*)&As[(mi*16+lr)*72 + c*8];
#pragma unroll
      for (int ni=0;ni<4;ni++) {
        const int n = wv*64 + ni*16 + lr;
        bF[ni].u = *(const uint4*)&Bs[n*64 + (c ^ (n&7))*8];
      }
#pragma unroll
      for (int mi=0;mi<4;mi++)
#pragma unroll
        for (int ni=0;ni<4;ni++)
          acc[mi][ni] = __builtin_amdgcn_mfma_f32_16x16x32_bf16(aF[mi].v, bF[ni].v, acc[mi][ni], 0,0,0);
    }
    __syncthreads();
  }

  const int sbase = m0 & 511;
  if (wv < 2) {
#pragma unroll
    for (int mi=0;mi<4;mi++) {
#pragma unroll
      for (int r=0;r<4;r++) {
        const int s = sbase + mi*16 + quad*4 + r;
        const int off = offsets[m0 + mi*16 + quad*4 + r];
#pragma unroll
        for (int ni=0;ni<4;ni++) {
          const int d = ni*16 + lr;
          const float v = acc[mi][ni][r];
          const float p = acc[mi][ni^2][r];
          const float rot = (ni < 2) ? -p : p;
          const float cc  = cosT[off*Dn + d];
          const float sn  = sinT[off*Dn + d];
          Kbuf[((size_t)(bk*512 + s))*128 + wv*64 + d] = bf16_1(v*cc + rot*sn);
        }
      }
    }
  } else {
    const int nbase = (wv - 2) * 64;
#pragma unroll
    for (int mi=0;mi<4;mi++) {
#pragma unroll
      for (int ni=0;ni<4;ni++) {
        const int np = nbase + ni*16 + lr;
        const int s  = sbase + mi*16 + quad*4;
        uint2 pk;
        pk.x = pack_bf16(acc[mi][ni][0], acc[mi][ni][1]);
        pk.y = pack_bf16(acc[mi][ni][2], acc[mi][ni][3]);
        *(uint2*)&Vt[((size_t)(bk*128 + np))*512 + s] = pk;
      }
    }
  }
}

__global__ __launch_bounds__(256)
void attn_kernel(const float* __restrict__ xq, const uint16_t* __restrict__ Kbuf,
                 const uint16_t* __restrict__ Vt, const int* __restrict__ lengths,
                 uint16_t* __restrict__ attn_out)
{
  __shared__ __align__(16) uint16_t Ks [128*72];
  __shared__ __align__(16) uint16_t Vts[64*136];
  __shared__ __align__(16) uint16_t Ps [4*16*136];

  const int t = threadIdx.x;
  const int bk = blockIdx.x >> 1, kvh = blockIdx.x & 1;
  const int w = t >> 6, lane = t & 63;
  const int quad = lane >> 4, lr = lane & 15;
  const int h = kvh*4 + w;
  const int len = lengths[bk];
  const int nc = (len + 127) >> 7;

  FragU aQ[2];
#pragma unroll
  for (int kk=0;kk<2;kk++) {
    const float* qp = &xq[lr*En + h*Dn + kk*32 + quad*8];
    float4 q0 = *(const float4*)qp;
    float4 q1 = *(const float4*)(qp + 4);
    aQ[kk].u.x = pack_bf16(q0.x*0.125f, q0.y*0.125f);
    aQ[kk].u.y = pack_bf16(q0.z*0.125f, q0.w*0.125f);
    aQ[kk].u.z = pack_bf16(q1.x*0.125f, q1.y*0.125f);
    aQ[kk].u.w = pack_bf16(q1.z*0.125f, q1.w*0.125f);
  }

  float m_run[4], l_run[4], alpha[4];
  f32x4 oacc[4];
#pragma unroll
  for (int r=0;r<4;r++){ m_run[r] = -3.0e38f; l_run[r] = 0.f; }
#pragma unroll
  for (int nd=0;nd<4;nd++) oacc[nd] = (f32x4){0.f,0.f,0.f,0.f};

  const int krow = t >> 1, kseg = t & 1;
  const int vrow = t >> 2, vseg = t & 3;
  const uint16_t* gK = &Kbuf[((size_t)(bk*512 + krow))*128 + kvh*64 + kseg*32];
  const uint16_t* gV = &Vt [((size_t)(bk*128 + kvh*64 + vrow))*512 + vseg*32];

  uint4 k0, k1, k2, k3, v0, v1, v2, v3;

#define PREF(c) do {                                           \
    const uint16_t* g_  = gK + (size_t)(c)*16384;              \
    k0 = *(const uint4*)g_;      k1 = *(const uint4*)(g_+8);   \
    k2 = *(const uint4*)(g_+16); k3 = *(const uint4*)(g_+24);  \
    const uint16_t* gv_ = gV + (c)*128;                        \
    v0 = *(const uint4*)gv_;      v1 = *(const uint4*)(gv_+8); \
    v2 = *(const uint4*)(gv_+16); v3 = *(const uint4*)(gv_+24);\
  } while(0)

  PREF(0);

  for (int c = 0; c < nc; ++c) {
    const int s0 = c * 128;
    __syncthreads();
    {
      uint16_t* dst = &Ks[krow*72 + kseg*32];
      *(uint4*)dst = k0; *(uint4*)(dst+8) = k1;
      *(uint4*)(dst+16) = k2; *(uint4*)(dst+24) = k3;
      uint16_t* dv = &Vts[vrow*136 + vseg*32];
      *(uint4*)dv = v0; *(uint4*)(dv+8) = v1;
      *(uint4*)(dv+16) = v2; *(uint4*)(dv+24) = v3;
    }
    if (c + 1 < nc) PREF(c + 1);
    __builtin_amdgcn_sched_barrier(0);
    asm volatile("s_waitcnt lgkmcnt(0)" ::: "memory");
    __builtin_amdgcn_s_barrier();
    __builtin_amdgcn_sched_barrier(0);

    f32x4 sc[8];
    __builtin_amdgcn_s_setprio(1);
#pragma unroll
    for (int ni=0;ni<8;ni++) {
      FragU b0, b1;
      b0.u = *(const uint4*)&Ks[(ni*16+lr)*72 + quad*8];
      b1.u = *(const uint4*)&Ks[(ni*16+lr)*72 + 32 + quad*8];
      f32x4 a = (f32x4){0.f,0.f,0.f,0.f};
      a = __builtin_amdgcn_mfma_f32_16x16x32_bf16(aQ[0].v, b0.v, a, 0,0,0);
      a = __builtin_amdgcn_mfma_f32_16x16x32_bf16(aQ[1].v, b1.v, a, 0,0,0);
      sc[ni] = a;
    }
    __builtin_amdgcn_s_setprio(0);
#pragma unroll
    for (int ni=0;ni<8;ni++)
      if (s0 + ni*16 + lr >= len)
        sc[ni] = (f32x4){-3.0e38f,-3.0e38f,-3.0e38f,-3.0e38f};

#pragma unroll
    for (int r=0;r<4;r++) {
      float mx = sc[0][r];
#pragma unroll
      for (int ni=1;ni<8;ni++) mx = fmaxf(mx, sc[ni][r]);
#pragma unroll
      for (int o=1;o<16;o<<=1) mx = fmaxf(mx, __shfl_xor(mx, o, 16));
      const float mnew = fmaxf(m_run[r], mx);
      alpha[r] = __expf(m_run[r] - mnew);
      m_run[r] = mnew;
      float ssum = 0.f;
#pragma unroll
      for (int ni=0;ni<8;ni++) {
        float p = __expf(sc[ni][r] - mnew);
        sc[ni][r] = p;
        ssum += p;
      }
#pragma unroll
      for (int o=1;o<16;o<<=1) ssum += __shfl_xor(ssum, o, 16);
      l_run[r] = l_run[r]*alpha[r] + ssum;
    }

#pragma unroll
    for (int ni=0;ni<8;ni++)
#pragma unroll
      for (int r=0;r<4;r++)
        Ps[(w*16 + quad*4 + r)*136 + ni*16 + lr] = bf16_1(sc[ni][r]);

#pragma unroll
    for (int nd=0;nd<4;nd++)
#pragma unroll
      for (int r=0;r<4;r++) oacc[nd][r] *= alpha[r];

    __builtin_amdgcn_s_setprio(1);
#pragma unroll
    for (int kk=0;kk<4;kk++) {
      FragU aP;
      aP.u = *(const uint4*)&Ps[(w*16 + lr)*136 + kk*32 + quad*8];
#pragma unroll
      for (int nd=0;nd<4;nd++) {
        FragU bV;
        bV.u = *(const uint4*)&Vts[(nd*16+lr)*136 + kk*32 + quad*8];
        oacc[nd] = __builtin_amdgcn_mfma_f32_16x16x32_bf16(aP.v, bV.v, oacc[nd], 0,0,0);
      }
    }
    __builtin_amdgcn_s_setprio(0);
  }
#undef PREF

#pragma unroll
  for (int r=0;r<4;r++) {
    const float rs = 1.0f / l_run[r];
    const int l = quad*4 + r;
#pragma unroll
    for (int nd=0;nd<4;nd++)
      attn_out[((size_t)(bk*16 + l))*512 + h*64 + nd*16 + lr] = bf16_1(oacc[nd][r] * rs);
  }
}

__global__ __launch_bounds__(256)
void oproj_kernel(const uint16_t* __restrict__ Ab, const uint16_t* __restrict__ Wob,
                  float* __restrict__ out)
{
  __shared__ __align__(16) uint16_t As[128*72];
  __shared__ __align__(16) uint16_t Bs[128*72];
  const int t = threadIdx.x;
  const int m0 = (blockIdx.x >> 2) * 128;
  const int n0 = (blockIdx.x & 3) * 128;
  const int lane = t & 63, wv = t >> 6;
  const int quad = lane >> 4, lr = lane & 15;
  const int wm = wv >> 1, wn = wv & 1;

  f32x4 acc[4][4];
#pragma unroll
  for (int i=0;i<4;i++)
#pragma unroll
    for (int j=0;j<4;j++) acc[i][j] = (f32x4){0.f,0.f,0.f,0.f};

  const int srow = t >> 3, sseg = t & 7;
  for (int kb = 0; kb < 8; ++kb) {
#pragma unroll
    for (int j = 0; j < 4; ++j) {
      const int row = srow + 32*j;
      *(uint4*)&As[row*72 + sseg*8] = *(const uint4*)&Ab [(size_t)(m0+row)*512 + kb*64 + sseg*8];
      *(uint4*)&Bs[row*72 + sseg*8] = *(const uint4*)&Wob[(size_t)(n0+row)*512 + kb*64 + sseg*8];
    }
    __syncthreads();
#pragma unroll
    for (int kk = 0; kk < 2; ++kk) {
      const int c = kk*4 + quad;
      FragU aF[4], bF[4];
#pragma unroll
      for (int mi=0;mi<4;mi++) aF[mi].u = *(const uint4*)&As[(wm*64+mi*16+lr)*72 + c*8];
#pragma unroll
      for (int ni=0;ni<4;ni++) bF[ni].u = *(const uint4*)&Bs[(wn*64+ni*16+lr)*72 + c*8];
#pragma unroll
      for (int mi=0;mi<4;mi++)
#pragma unroll
        for (int ni=0;ni<4;ni++)
          acc[mi][ni] = __builtin_amdgcn_mfma_f32_16x16x32_bf16(aF[mi].v, bF[ni].v, acc[mi][ni], 0,0,0);
    }
    __syncthreads();
  }
#pragma unroll
  for (int mi=0;mi<4;mi++)
#pragma unroll
    for (int r=0;r<4;r++)
#pragma unroll
      for (int ni=0;ni<4;ni++)
        out[(size_t)(m0 + wm*64 + mi*16 + quad*4 + r)*512 + n0 + wn*64 + ni*16 + lr] = acc[mi][ni][r];
}

// ---------------- launch ----------------
extern "C" void kernel_launch(void* const* d_in, const int* in_sizes, int n_in,
                              void* d_out, int out_size, void* d_ws, size_t ws_size,
                              hipStream_t stream)
{
  const float* spike   = (const float*)d_in[0];
  const int*   offsets = (const int*)d_in[1];
  const int*   lengths = (const int*)d_in[2];
  const float* cosT    = (const float*)d_in[3];
  const float* sinT    = (const float*)d_in[4];
  const float* latent  = (const float*)d_in[5];
  const float* Wq      = (const float*)d_in[6];
  const float* Wk      = (const float*)d_in[7];
  const float* Wv      = (const float*)d_in[8];
  const float* Wo      = (const float*)d_in[9];
  float* out = (float*)d_out;

  char* ws = (char*)d_ws;
  float*    xq   = (float*)ws;                                  // 64 KB reserved
  uint4*    Wsw  = (uint4*)(ws + 65536);                        // 256 KB
  uint4*    Wob  = (uint4*)(ws + 65536 + 262144);               // 512 KB
  uint16_t* Kbuf = (uint16_t*)(ws + 1048576);                   // 32 MB
  uint16_t* Vt   = (uint16_t*)(ws + 1048576 + 33554432ull);     // 32 MB
  uint16_t* attn_out = (uint16_t*)(ws + 1048576 + 67108864ull); // 4 MB

  void* args[] = { (void*)&spike, (void*)&offsets, (void*)&lengths, (void*)&cosT,
                   (void*)&sinT, (void*)&latent, (void*)&Wq, (void*)&Wk,
                   (void*)&Wv, (void*)&Wo, (void*)&xq, (void*)&Wsw, (void*)&Wob,
                   (void*)&Kbuf, (void*)&Vt, (void*)&attn_out, (void*)&out };
  hipError_t e = hipLaunchCooperativeKernel((const void*)mega_kernel,
                                            dim3(512), dim3(256), args, 0, stream);
  if (e != hipSuccess) {
    // Fallback: proven 4-kernel pipeline (R4)
    hipLaunchKernelGGL(prep_kernel,   dim3(704),  dim3(256), 0, stream,
                       latent, Wq, Wk, Wv, Wo, xq, Wsw, Wob);
    hipLaunchKernelGGL(kvproj_kernel, dim3(2048), dim3(256), 0, stream,
                       spike, offsets, cosT, sinT, Wsw, lengths, Kbuf, Vt);
    hipLaunchKernelGGL(attn_kernel,   dim3(512),  dim3(256), 0, stream,
                       xq, Kbuf, Vt, lengths, attn_out);
    hipLaunchKernelGGL(oproj_kernel,  dim3(128),  dim3(256), 0, stream,
                       attn_out, (const uint16_t*)Wob, out);
  }
}

// Round 6
// 429.083 us; speedup vs baseline: 1.3951x; 1.3951x over previous
//
#include <hip/hip_runtime.h>
#include <hip/hip_bf16.h>
#include <stdint.h>

typedef __attribute__((ext_vector_type(8))) short bf16x8;
typedef __attribute__((ext_vector_type(4))) float f32x4;

union FragU { uint4 u; bf16x8 v; };

#define Bn 16
#define Kn 16
#define Sn 512
#define En 512
#define Ln 16
#define Hn 8
#define Dn 64

__device__ __forceinline__ uint32_t pack_bf16(float lo, float hi) {
  uint32_t a = __float_as_uint(lo) + 0x8000u;
  uint32_t b = __float_as_uint(hi) + 0x8000u;
  return __builtin_amdgcn_perm(b, a, 0x07060302u);  // [b.hi16 : a.hi16]
}
__device__ __forceinline__ uint16_t bf16_1(float x) {
  __hip_bfloat16 h = __float2bfloat16(x);
  return *(uint16_t*)&h;
}
__device__ __forceinline__ void gload_lds16(const void* g, void* l) {
  __builtin_amdgcn_global_load_lds(
      (const __attribute__((address_space(1))) uint32_t*)g,
      (__attribute__((address_space(3))) uint32_t*)l, 16, 0, 0);
}

// ---------------- Kernel 0: fused prep (R4-proven) ----------------
// blocks 0..511   : xq = latent_query @ Wq^T (column j = blockIdx)
// blocks 512..575 : Wk/Wv -> Wsw (bf16, XOR bank swizzle baked in)
// blocks 576..703 : Wo -> Wob (bf16 row-major)
__global__ __launch_bounds__(256)
void prep_kernel(const float* __restrict__ latent, const float* __restrict__ Wq,
                 const float* __restrict__ Wk, const float* __restrict__ Wv,
                 const float* __restrict__ Wo,
                 float* __restrict__ xq, uint4* __restrict__ Wsw, uint4* __restrict__ Wob)
{
  __shared__ float red[4][Ln];
  const int t = threadIdx.x;
  const int blk = blockIdx.x;
  if (blk < 512) {
    const int j = blk;
    const float w0 = Wq[j*En + t];
    const float w1 = Wq[j*En + t + 256];
    float part[Ln];
#pragma unroll
    for (int l = 0; l < Ln; ++l)
      part[l] = w0 * latent[l*En + t] + w1 * latent[l*En + t + 256];
#pragma unroll
    for (int l = 0; l < Ln; ++l) {
      float v = part[l];
#pragma unroll
      for (int off = 32; off > 0; off >>= 1) v += __shfl_down(v, off, 64);
      part[l] = v;
    }
    const int lane = t & 63, wv = t >> 6;
    if (lane == 0) {
#pragma unroll
      for (int l = 0; l < Ln; ++l) red[wv][l] = part[l];
    }
    __syncthreads();
    if (t < Ln)
      xq[t*En + j] = red[0][t] + red[1][t] + red[2][t] + red[3][t];
  } else if (blk < 576) {
    const int idx = (blk - 512)*256 + t;
    const int kb = idx >> 11;
    const int rem = idx & 2047;
    const int n = rem >> 3, p = rem & 7;
    const int c = p ^ (n & 7);
    const float* src = (n < 128 ? Wk + (size_t)n*En : Wv + (size_t)(n-128)*En) + kb*64 + c*8;
    float4 v0 = *(const float4*)src;
    float4 v1 = *(const float4*)(src+4);
    uint4 o;
    o.x = pack_bf16(v0.x,v0.y); o.y = pack_bf16(v0.z,v0.w);
    o.z = pack_bf16(v1.x,v1.y); o.w = pack_bf16(v1.z,v1.w);
    Wsw[idx] = o;
  } else {
    const int idx = (blk - 576)*256 + t;
    const float* src = Wo + (size_t)idx*8;
    float4 v0 = *(const float4*)src;
    float4 v1 = *(const float4*)(src+4);
    uint4 o;
    o.x = pack_bf16(v0.x,v0.y); o.y = pack_bf16(v0.z,v0.w);
    o.z = pack_bf16(v1.x,v1.y); o.w = pack_bf16(v1.z,v1.w);
    Wob[idx] = o;
  }
}

// ---------------- Kernel 1: KV projection, retiled 128m x 256n, BK=64 ----------------
// m93-style M-growth: 2x MFMA per barrier, half the weight staging per row.
// Ragged skip stays 64-granular: block-uniform M_act in {4,8}; inactive half's
// MFMAs/staging are skipped, epilogue writes acc(=0) unconditionally so the
// inactive half lands as exact zeros (finite -> NaN-proof through attn's 0*V).
__global__ __launch_bounds__(256, 2)
void kvproj_kernel(const float* __restrict__ spike, const int* __restrict__ offsets,
                   const float* __restrict__ cosT, const float* __restrict__ sinT,
                   const uint4* __restrict__ Wsw, const int* __restrict__ lengths,
                   uint16_t* __restrict__ Kbuf, uint16_t* __restrict__ Vt)
{
  __shared__ __align__(16) uint16_t Bs[256*64];   // 32 KB, swizzled weight rows
  __shared__ __align__(16) uint16_t As[128*72];   // 18 KB, 128 spike rows + pad
  const int t = threadIdx.x;
  const int bk   = blockIdx.x >> 2;
  const int tile = blockIdx.x & 3;
  const int len = lengths[bk];
  if (tile * 128 >= len) return;                  // fully-masked tile
  const int m0 = blockIdx.x * 128;                // = bk*512 + tile*128
  const int M_act = (len > tile*128 + 64) ? 8 : 4;
  const int lane = t & 63, wv = t >> 6;
  const int quad = lane >> 4, lr = lane & 15;

  f32x4 acc[8][4];
#pragma unroll
  for (int i=0;i<8;i++)
#pragma unroll
    for (int j=0;j<4;j++) acc[i][j] = (f32x4){0.f,0.f,0.f,0.f};

  const int arow = t >> 3;
  const int aseg = t & 7;

  for (int kb = 0; kb < 8; ++kb) {
    // weights: 32 KB staged once for 128 rows (was: once per 64 rows)
    const char* gb = (const char*)(Wsw + kb*2048) + (wv*64 + lane)*16;
    char* lb = (char*)Bs + wv*1024;
#pragma unroll
    for (int i = 0; i < 8; ++i)
      gload_lds16(gb + i*4096, lb + i*4096);
    // spike rows (skip inactive half: j>=2 only when M_act==8)
#pragma unroll
    for (int j = 0; j < 4; ++j) {
      if (j < 2 || M_act == 8) {
        const int row = arow + 32*j;
        const float* src = &spike[(size_t)(m0+row)*En + kb*64 + aseg*8];
        float4 v0 = *(const float4*)src;
        float4 v1 = *(const float4*)(src+4);
        uint4 o;
        o.x = pack_bf16(v0.x,v0.y); o.y = pack_bf16(v0.z,v0.w);
        o.z = pack_bf16(v1.x,v1.y); o.w = pack_bf16(v1.z,v1.w);
        *(uint4*)&As[row*72 + aseg*8] = o;
      }
    }
    __syncthreads();
#pragma unroll
    for (int kk = 0; kk < 2; ++kk) {
      const int c = kk*4 + quad;
      FragU bF[4];
#pragma unroll
      for (int ni=0;ni<4;ni++) {
        const int n = wv*64 + ni*16 + lr;
        bF[ni].u = *(const uint4*)&Bs[n*64 + (c ^ (n&7))*8];
      }
#pragma unroll
      for (int mi=0;mi<8;mi++) {
        if (mi < M_act) {
          FragU aF;
          aF.u = *(const uint4*)&As[(mi*16+lr)*72 + c*8];
#pragma unroll
          for (int ni=0;ni<4;ni++)
            acc[mi][ni] = __builtin_amdgcn_mfma_f32_16x16x32_bf16(aF.v, bF[ni].v, acc[mi][ni], 0,0,0);
        }
      }
    }
    __syncthreads();
  }

  const int sbase = m0 & 511;                     // = tile*128
  if (wv < 2) {
#pragma unroll
    for (int mi=0;mi<8;mi++) {
#pragma unroll
      for (int r=0;r<4;r++) {
        const int s = sbase + mi*16 + quad*4 + r;
        const int off = offsets[m0 + mi*16 + quad*4 + r];
#pragma unroll
        for (int ni=0;ni<4;ni++) {
          const int d = ni*16 + lr;
          const float v = acc[mi][ni][r];
          const float p = acc[mi][ni^2][r];
          const float rot = (ni < 2) ? -p : p;
          const float cc  = cosT[off*Dn + d];
          const float sn  = sinT[off*Dn + d];
          Kbuf[((size_t)(bk*512 + s))*128 + wv*64 + d] = bf16_1(v*cc + rot*sn);
        }
      }
    }
  } else {
    const int nbase = (wv - 2) * 64;
#pragma unroll
    for (int mi=0;mi<8;mi++) {
#pragma unroll
      for (int ni=0;ni<4;ni++) {
        const int np = nbase + ni*16 + lr;
        const int s  = sbase + mi*16 + quad*4;
        uint2 pk;
        pk.x = pack_bf16(acc[mi][ni][0], acc[mi][ni][1]);
        pk.y = pack_bf16(acc[mi][ni][2], acc[mi][ni][3]);
        *(uint2*)&Vt[((size_t)(bk*128 + np))*512 + s] = pk;
      }
    }
  }
}

// ---------------- Kernel 2: flash attention (R4-proven) ----------------
__global__ __launch_bounds__(256)
void attn_kernel(const float* __restrict__ xq, const uint16_t* __restrict__ Kbuf,
                 const uint16_t* __restrict__ Vt, const int* __restrict__ lengths,
                 uint16_t* __restrict__ attn_out)
{
  __shared__ __align__(16) uint16_t Ks [128*72];
  __shared__ __align__(16) uint16_t Vts[64*136];
  __shared__ __align__(16) uint16_t Ps [4*16*136];

  const int t = threadIdx.x;
  const int bk = blockIdx.x >> 1, kvh = blockIdx.x & 1;
  const int w = t >> 6, lane = t & 63;
  const int quad = lane >> 4, lr = lane & 15;
  const int h = kvh*4 + w;
  const int len = lengths[bk];
  const int nc = (len + 127) >> 7;   // 1..4 chunks of 128

  FragU aQ[2];
#pragma unroll
  for (int kk=0;kk<2;kk++) {
    const float* qp = &xq[lr*En + h*Dn + kk*32 + quad*8];
    float4 q0 = *(const float4*)qp;
    float4 q1 = *(const float4*)(qp + 4);
    aQ[kk].u.x = pack_bf16(q0.x*0.125f, q0.y*0.125f);
    aQ[kk].u.y = pack_bf16(q0.z*0.125f, q0.w*0.125f);
    aQ[kk].u.z = pack_bf16(q1.x*0.125f, q1.y*0.125f);
    aQ[kk].u.w = pack_bf16(q1.z*0.125f, q1.w*0.125f);
  }

  float m_run[4], l_run[4], alpha[4];
  f32x4 oacc[4];
#pragma unroll
  for (int r=0;r<4;r++){ m_run[r] = -3.0e38f; l_run[r] = 0.f; }
#pragma unroll
  for (int nd=0;nd<4;nd++) oacc[nd] = (f32x4){0.f,0.f,0.f,0.f};

  const int krow = t >> 1, kseg = t & 1;
  const int vrow = t >> 2, vseg = t & 3;
  const uint16_t* gK = &Kbuf[((size_t)(bk*512 + krow))*128 + kvh*64 + kseg*32];
  const uint16_t* gV = &Vt [((size_t)(bk*128 + kvh*64 + vrow))*512 + vseg*32];

  uint4 k0, k1, k2, k3, v0, v1, v2, v3;   // named -> guaranteed VGPRs

#define PREF(c) do {                                           \
    const uint16_t* g_  = gK + (size_t)(c)*16384;              \
    k0 = *(const uint4*)g_;      k1 = *(const uint4*)(g_+8);   \
    k2 = *(const uint4*)(g_+16); k3 = *(const uint4*)(g_+24);  \
    const uint16_t* gv_ = gV + (c)*128;                        \
    v0 = *(const uint4*)gv_;      v1 = *(const uint4*)(gv_+8); \
    v2 = *(const uint4*)(gv_+16); v3 = *(const uint4*)(gv_+24);\
  } while(0)

  PREF(0);

  for (int c = 0; c < nc; ++c) {
    const int s0 = c * 128;
    __syncthreads();   // prev chunk's LDS reads done; also waits chunk-c loads
    {
      uint16_t* dst = &Ks[krow*72 + kseg*32];
      *(uint4*)dst = k0; *(uint4*)(dst+8) = k1;
      *(uint4*)(dst+16) = k2; *(uint4*)(dst+24) = k3;
      uint16_t* dv = &Vts[vrow*136 + vseg*32];
      *(uint4*)dv = v0; *(uint4*)(dv+8) = v1;
      *(uint4*)(dv+16) = v2; *(uint4*)(dv+24) = v3;
    }
    if (c + 1 < nc) PREF(c + 1);               // issue next-chunk loads now
    __builtin_amdgcn_sched_barrier(0);         // keep them above the barrier
    asm volatile("s_waitcnt lgkmcnt(0)" ::: "memory");  // ds_writes visible; vmcnt untouched
    __builtin_amdgcn_s_barrier();
    __builtin_amdgcn_sched_barrier(0);

    f32x4 sc[8];
    __builtin_amdgcn_s_setprio(1);
#pragma unroll
    for (int ni=0;ni<8;ni++) {
      FragU b0, b1;
      b0.u = *(const uint4*)&Ks[(ni*16+lr)*72 + quad*8];
      b1.u = *(const uint4*)&Ks[(ni*16+lr)*72 + 32 + quad*8];
      f32x4 a = (f32x4){0.f,0.f,0.f,0.f};
      a = __builtin_amdgcn_mfma_f32_16x16x32_bf16(aQ[0].v, b0.v, a, 0,0,0);
      a = __builtin_amdgcn_mfma_f32_16x16x32_bf16(aQ[1].v, b1.v, a, 0,0,0);
      sc[ni] = a;
    }
    __builtin_amdgcn_s_setprio(0);
#pragma unroll
    for (int ni=0;ni<8;ni++)
      if (s0 + ni*16 + lr >= len)
        sc[ni] = (f32x4){-3.0e38f,-3.0e38f,-3.0e38f,-3.0e38f};

#pragma unroll
    for (int r=0;r<4;r++) {
      float mx = sc[0][r];
#pragma unroll
      for (int ni=1;ni<8;ni++) mx = fmaxf(mx, sc[ni][r]);
#pragma unroll
      for (int o=1;o<16;o<<=1) mx = fmaxf(mx, __shfl_xor(mx, o, 16));
      const float mnew = fmaxf(m_run[r], mx);
      alpha[r] = __expf(m_run[r] - mnew);
      m_run[r] = mnew;
      float ssum = 0.f;
#pragma unroll
      for (int ni=0;ni<8;ni++) {
        float p = __expf(sc[ni][r] - mnew);
        sc[ni][r] = p;
        ssum += p;
      }
#pragma unroll
      for (int o=1;o<16;o<<=1) ssum += __shfl_xor(ssum, o, 16);
      l_run[r] = l_run[r]*alpha[r] + ssum;
    }

#pragma unroll
    for (int ni=0;ni<8;ni++)
#pragma unroll
      for (int r=0;r<4;r++)
        Ps[(w*16 + quad*4 + r)*136 + ni*16 + lr] = bf16_1(sc[ni][r]);

#pragma unroll
    for (int nd=0;nd<4;nd++)
#pragma unroll
      for (int r=0;r<4;r++) oacc[nd][r] *= alpha[r];

    __builtin_amdgcn_s_setprio(1);
#pragma unroll
    for (int kk=0;kk<4;kk++) {
      FragU aP;
      aP.u = *(const uint4*)&Ps[(w*16 + lr)*136 + kk*32 + quad*8];
#pragma unroll
      for (int nd=0;nd<4;nd++) {
        FragU bV;
        bV.u = *(const uint4*)&Vts[(nd*16+lr)*136 + kk*32 + quad*8];
        oacc[nd] = __builtin_amdgcn_mfma_f32_16x16x32_bf16(aP.v, bV.v, oacc[nd], 0,0,0);
      }
    }
    __builtin_amdgcn_s_setprio(0);
  }
#undef PREF

#pragma unroll
  for (int r=0;r<4;r++) {
    const float rs = 1.0f / l_run[r];
    const int l = quad*4 + r;
#pragma unroll
    for (int nd=0;nd<4;nd++)
      attn_out[((size_t)(bk*16 + l))*512 + h*64 + nd*16 + lr] = bf16_1(oacc[nd][r] * rs);
  }
}

// ---------------- Kernel 3: oproj (R4-proven, 128x128 tiles) ----------------
__global__ __launch_bounds__(256)
void oproj_kernel(const uint16_t* __restrict__ Ab, const uint16_t* __restrict__ Wob,
                  float* __restrict__ out)
{
  __shared__ __align__(16) uint16_t As[128*72];
  __shared__ __align__(16) uint16_t Bs[128*72];
  const int t = threadIdx.x;
  const int m0 = (blockIdx.x >> 2) * 128;
  const int n0 = (blockIdx.x & 3) * 128;
  const int lane = t & 63, wv = t >> 6;
  const int quad = lane >> 4, lr = lane & 15;
  const int wm = wv >> 1, wn = wv & 1;

  f32x4 acc[4][4];
#pragma unroll
  for (int i=0;i<4;i++)
#pragma unroll
    for (int j=0;j<4;j++) acc[i][j] = (f32x4){0.f,0.f,0.f,0.f};

  const int srow = t >> 3, sseg = t & 7;
  for (int kb = 0; kb < 8; ++kb) {
#pragma unroll
    for (int j = 0; j < 4; ++j) {
      const int row = srow + 32*j;
      *(uint4*)&As[row*72 + sseg*8] = *(const uint4*)&Ab [(size_t)(m0+row)*512 + kb*64 + sseg*8];
      *(uint4*)&Bs[row*72 + sseg*8] = *(const uint4*)&Wob[(size_t)(n0+row)*512 + kb*64 + sseg*8];
    }
    __syncthreads();
#pragma unroll
    for (int kk = 0; kk < 2; ++kk) {
      const int c = kk*4 + quad;
      FragU aF[4], bF[4];
#pragma unroll
      for (int mi=0;mi<4;mi++) aF[mi].u = *(const uint4*)&As[(wm*64+mi*16+lr)*72 + c*8];
#pragma unroll
      for (int ni=0;ni<4;ni++) bF[ni].u = *(const uint4*)&Bs[(wn*64+ni*16+lr)*72 + c*8];
#pragma unroll
      for (int mi=0;mi<4;mi++)
#pragma unroll
        for (int ni=0;ni<4;ni++)
          acc[mi][ni] = __builtin_amdgcn_mfma_f32_16x16x32_bf16(aF[mi].v, bF[ni].v, acc[mi][ni], 0,0,0);
    }
    __syncthreads();
  }
#pragma unroll
  for (int mi=0;mi<4;mi++)
#pragma unroll
    for (int r=0;r<4;r++)
#pragma unroll
      for (int ni=0;ni<4;ni++)
        out[(size_t)(m0 + wm*64 + mi*16 + quad*4 + r)*512 + n0 + wn*64 + ni*16 + lr] = acc[mi][ni][r];
}

// ---------------- launch ----------------
extern "C" void kernel_launch(void* const* d_in, const int* in_sizes, int n_in,
                              void* d_out, int out_size, void* d_ws, size_t ws_size,
                              hipStream_t stream)
{
  const float* spike   = (const float*)d_in[0];
  const int*   offsets = (const int*)d_in[1];
  const int*   lengths = (const int*)d_in[2];
  const float* cosT    = (const float*)d_in[3];
  const float* sinT    = (const float*)d_in[4];
  const float* latent  = (const float*)d_in[5];
  const float* Wq      = (const float*)d_in[6];
  const float* Wk      = (const float*)d_in[7];
  const float* Wv      = (const float*)d_in[8];
  const float* Wo      = (const float*)d_in[9];
  float* out = (float*)d_out;

  char* ws = (char*)d_ws;
  float*    xq   = (float*)ws;                                  // 64 KB reserved
  uint4*    Wsw  = (uint4*)(ws + 65536);                        // 256 KB
  uint4*    Wob  = (uint4*)(ws + 65536 + 262144);               // 512 KB
  uint16_t* Kbuf = (uint16_t*)(ws + 1048576);                   // 32 MB
  uint16_t* Vt   = (uint16_t*)(ws + 1048576 + 33554432ull);     // 32 MB
  uint16_t* attn_out = (uint16_t*)(ws + 1048576 + 67108864ull); // 4 MB

  hipLaunchKernelGGL(prep_kernel,   dim3(704),  dim3(256), 0, stream,
                     latent, Wq, Wk, Wv, Wo, xq, Wsw, Wob);
  hipLaunchKernelGGL(kvproj_kernel, dim3(1024), dim3(256), 0, stream,
                     spike, offsets, cosT, sinT, Wsw, lengths, Kbuf, Vt);
  hipLaunchKernelGGL(attn_kernel,   dim3(512),  dim3(256), 0, stream,
                     xq, Kbuf, Vt, lengths, attn_out);
  hipLaunchKernelGGL(oproj_kernel,  dim3(128),  dim3(256), 0, stream,
                     attn_out, (const uint16_t*)Wob, out);
}